// Round 4
// baseline (941.179 us; speedup 1.0000x reference)
//
#include <hip/hip_runtime.h>
#include <stdint.h>

typedef __bf16 bf16x8 __attribute__((ext_vector_type(8)));
typedef __bf16 bf16x4 __attribute__((ext_vector_type(4)));
typedef float  f32x4  __attribute__((ext_vector_type(4)));

// async 16B global -> LDS (dest = wave-uniform base + lane*16)
__device__ __forceinline__ void gl_lds16(const void* g, void* l) {
  __builtin_amdgcn_global_load_lds(
      (const __attribute__((address_space(1))) void*)g,
      (__attribute__((address_space(3))) void*)l, 16, 0, 0);
}

// out[C x R] (bf16) = in[R x C]^T (fp32) — tiny weight matrices only
__global__ void transpose_cvt(const float* __restrict__ in, __bf16* __restrict__ out,
                              int R, int Ccols) {
  int idx = blockIdx.x * 256 + threadIdx.x;
  if (idx < R * Ccols) {
    int r = idx / Ccols, c = idx % Ccols;
    out[(size_t)c * R + r] = (__bf16)in[(size_t)r * Ccols + c];
  }
}

// C = A @ B.  A:[MxK] row-major (fp32 if AF32 else bf16), BT:[NxK] bf16 row-major.
// STREAMING tile: BM=16, BN=128, BK=64. 256 thr = 4 waves; wave w owns output
// cols w*32..w*32+31 (2 frags of 16x16), all waves share the 16 A rows.
// Grid: (M/16, N/128). NO split-K: each block runs full K with double-buffered
// LDS (stage(next) before compute(cur), one vmcnt(0)+s_barrier per K-step).
// B-panel is small (<=2.56 MB) -> L2-resident; HBM traffic = A + C only.
// MODE 1: bf16 out (+bias/relu; transC=1 -> C[col*ldc+row], packed 4-row stores).
// MODE 2: fp32 out (+bias), row-major.
template<bool AF32, int MODE>
__global__ __launch_bounds__(256) void gemm16(
    const void* __restrict__ A, int lda,
    const __bf16* __restrict__ BT, int ldbt,
    void* __restrict__ C, int ldc,
    const float* __restrict__ bias,
    int M, int N, int K, int do_relu, int transC)
{
  constexpr int ABYTES = AF32 ? 4096 : 2048;   // [16][64] fp32 / bf16
  constexpr int BBYTES = 16384;                // [128][64] bf16
  constexpr int BUFB = ABYTES + BBYTES;
  __shared__ char smem[2 * BUFB];              // 40 KB (fp32) / 36 KB (bf16)

  const int tid  = threadIdx.x;
  const int lane = tid & 63;
  const int w    = tid >> 6;
  const int quad = lane >> 4, l15 = lane & 15;

  const int mblk = blockIdx.x * 16;
  const int nblk = blockIdx.y * 128;
  const int kend = K;

  f32x4 acc[2] = {};                           // wave's 2 N-frags x 4 rows

  // stage one 16x64 A-tile + 128x64 B-tile into buffer `buf`
  // (XOR-swizzled SOURCE k-units so the un-swizzled ds_reads are conflict-free)
  auto stage = [&](int buf, int kt) {
    char* sA = smem + buf * BUFB;
    char* sB = sA + ABYTES;
    const int klen = (kend - kt) < 64 ? (kend - kt) : 64;
    if (AF32) {
      // A fp32: 256 slots of 16B; row = slot>>4 (16 units/row), unit = p ^ row
      const float* Af = (const float*)A;
      int slot = tid;                       // = w*64 + lane  (base + lane*16 ok)
      int row = slot >> 4, p = slot & 15;
      int u = p ^ row;
      int rg = mblk + row; if (rg >= M) rg = M - 1;
      int ku = (u * 4 + 4 <= klen) ? (kt + u * 4) : kt;   // tail: garbage, zeroed at MFMA
      gl_lds16(Af + (size_t)rg * lda + ku, sA + slot * 16);
    } else {
      // A bf16: 128 slots; waves 0,1 only; row = slot>>3, unit = p ^ (row&7)
      if (w < 2) {
        const __bf16* Ab = (const __bf16*)A;
        int slot = w * 64 + lane;
        int row = slot >> 3, p = slot & 7;
        int u = p ^ (row & 7);
        int rg = mblk + row; if (rg >= M) rg = M - 1;
        int ku = (u * 8 + 8 <= klen) ? (kt + u * 8) : kt;
        gl_lds16(Ab + (size_t)rg * lda + ku, sA + slot * 16);
      }
    }
    // B: 1024 slots of 16B; row = slot>>3 (8 units/row), unit = p ^ (row&7)
    #pragma unroll
    for (int t = 0; t < 4; ++t) {
      int slot = (w * 4 + t) * 64 + lane;
      int row = slot >> 3, p = slot & 7;
      int u = p ^ (row & 7);
      int rg = nblk + row; if (rg >= N) rg = N - 1;
      int ku = (u * 8 + 8 <= klen) ? (kt + u * 8) : kt;
      gl_lds16(BT + (size_t)rg * ldbt + ku, sB + slot * 16);
    }
  };

  // prologue: fill buffer 0, drain, barrier
  int cur = 0;
  stage(0, 0);
  asm volatile("s_waitcnt vmcnt(0)" ::: "memory");
  __builtin_amdgcn_s_barrier();
  asm volatile("" ::: "memory");

  for (int kt = 0; kt < kend; kt += 64) {
    if (kt + 64 < kend) stage(cur ^ 1, kt + 64);   // prefetch next tile

    const int klen = (kend - kt) < 64 ? (kend - kt) : 64;
    char* sA = smem + cur * BUFB;
    char* sB = sA + ABYTES;

    #pragma unroll
    for (int ks = 0; ks < 2; ++ks) {               // two k=32 substeps
      // ---- A fragment: row l15, k = ks*32 + quad*8 .. +7 ----
      bf16x8 af;
      if (AF32) {
        int uw0 = ks * 8 + quad * 2;
        f32x4 lo = *(const f32x4*)(sA + l15 * 256 + ((uw0 ^ l15) * 16));
        f32x4 hi = *(const f32x4*)(sA + l15 * 256 + (((uw0 + 1) ^ l15) * 16));
        af[0] = (__bf16)lo[0]; af[1] = (__bf16)lo[1]; af[2] = (__bf16)lo[2]; af[3] = (__bf16)lo[3];
        af[4] = (__bf16)hi[0]; af[5] = (__bf16)hi[1]; af[6] = (__bf16)hi[2]; af[7] = (__bf16)hi[3];
      } else {
        int uw = ks * 4 + quad;
        af = *(const bf16x8*)(sA + l15 * 128 + ((uw ^ (l15 & 7)) * 16));
      }
      if (ks * 32 + quad * 8 + 8 > klen) {         // K tail: zero A side
        bf16x8 z = {};
        af = z;
      }
      // ---- B fragments + MFMA ----
      #pragma unroll
      for (int jj = 0; jj < 2; ++jj) {
        int nloc = w * 32 + jj * 16 + l15;
        bf16x8 bfr = *(const bf16x8*)(sB + nloc * 128 + (((ks * 4 + quad) ^ (nloc & 7)) * 16));
        acc[jj] = __builtin_amdgcn_mfma_f32_16x16x32_bf16(af, bfr, acc[jj], 0, 0, 0);
      }
    }

    asm volatile("s_waitcnt vmcnt(0)" ::: "memory");   // next tile landed
    __builtin_amdgcn_s_barrier();
    asm volatile("" ::: "memory");
    cur ^= 1;
  }

  // ---- epilogue. C/D frag: col = l15 (N side), row = quad*4 + r (M side) ----
  const int rowb = mblk + quad * 4;
  #pragma unroll
  for (int jj = 0; jj < 2; ++jj) {
    int col = nblk + w * 32 + jj * 16 + l15;
    if (col >= N) continue;
    float bv = bias ? bias[col] : 0.0f;
    if (MODE == 1 && transC) {
      // pack 4 consecutive rows of this column into one 8B store
      bf16x4 v;
      #pragma unroll
      for (int r = 0; r < 4; ++r) {
        float f = acc[jj][r] + bv;
        if (do_relu && f < 0.0f) f = 0.0f;
        v[r] = (__bf16)f;
      }
      if (rowb + 3 < M)
        *(bf16x4*)((__bf16*)C + (size_t)col * ldc + rowb) = v;
      else
        for (int r = 0; r < 4; ++r)
          if (rowb + r < M) ((__bf16*)C)[(size_t)col * ldc + rowb + r] = v[r];
    } else {
      #pragma unroll
      for (int r = 0; r < 4; ++r) {
        int row = rowb + r;
        if (row < M) {
          float f = acc[jj][r] + bv;
          if (do_relu && f < 0.0f) f = 0.0f;
          if (MODE == 1) ((__bf16*)C)[(size_t)row * ldc + col] = (__bf16)f;
          else           ((float*)C)[(size_t)row * ldc + col] = f;
        }
      }
    }
  }
}

extern "C" void kernel_launch(void* const* d_in, const int* in_sizes, int n_in,
                              void* d_out, int out_size, void* d_ws, size_t ws_size,
                              hipStream_t stream) {
  const float* x   = (const float*)d_in[0];  // [10000 x 512]
  const float* adj = (const float*)d_in[1];  // [10000 x 10000]
  const float* W1  = (const float*)d_in[2];  // [512 x 128]
  const float* b1  = (const float*)d_in[3];  // [128]
  const float* W2  = (const float*)d_in[4];  // [128 x 512]
  const float* b2  = (const float*)d_in[5];  // [512]
  float* out = (float*)d_out;                // [10000 x 512]

  const int Nn = 10000, NF = 512, NH = 128;

  // ws layout (bytes)
  char* ws = (char*)d_ws;
  __bf16* W1T = (__bf16*)(ws + 0);           // [128][512]   131072
  __bf16* W2T = (__bf16*)(ws + 131072);      // [512][128]   131072
  __bf16* xwT = (__bf16*)(ws + 262144);      // [128][10000] 2560000
  __bf16* hT  = (__bf16*)(ws + 2822144);     // [128][10000] 2560000
  __bf16* ah  = (__bf16*)(ws + 5382144);     // [10000][128] 2560000
  (void)ws_size;

  dim3 blk(256);
  const int MB = Nn / 16;                    // 625 (exact)

  hipLaunchKernelGGL(transpose_cvt, dim3((NF * NH + 255) / 256), blk, 0, stream, W1, W1T, NF, NH);
  hipLaunchKernelGGL(transpose_cvt, dim3((NF * NH + 255) / 256), blk, 0, stream, W2, W2T, NH, NF);

  // K1: xwT = (x @ W1)^T           M=10000 N=128 K=512
  hipLaunchKernelGGL((gemm16<true, 1>), dim3(MB, 1), blk, 0, stream,
                     (const void*)x, NF, W1T, NF, (void*)xwT, Nn, (const float*)nullptr,
                     Nn, NH, NF, 0, 1);
  // K2: hT = relu(adj @ xw + b1)^T M=10000 N=128 K=10000 (streaming, no split-K)
  hipLaunchKernelGGL((gemm16<true, 1>), dim3(MB, 1), blk, 0, stream,
                     (const void*)adj, Nn, xwT, Nn, (void*)hT, Nn, b1,
                     Nn, NH, Nn, 1, 1);
  // K3: ah = adj @ h               M=10000 N=128 K=10000, row-major bf16
  hipLaunchKernelGGL((gemm16<true, 1>), dim3(MB, 1), blk, 0, stream,
                     (const void*)adj, Nn, hT, Nn, (void*)ah, NH, (const float*)nullptr,
                     Nn, NH, Nn, 0, 0);
  // K4: out = ah @ W2 + b2         M=10000 N=512 K=128, fp32 out
  hipLaunchKernelGGL((gemm16<false, 2>), dim3(MB, 4), blk, 0, stream,
                     (const void*)ah, NH, W2T, NH, (void*)out, NF, b2,
                     Nn, NF, NH, 0, 0);
}